// Round 9
// baseline (30.258 us; speedup 1.0000x reference)
//
#include <hip/hip_runtime.h>

#define MM 16      // mixtures
#define DD 128     // visible dims
#define CC 50      // categories
#define BB 32768   // batch

// ---------------------------------------------------------------------------
// Kernel 1: lse_arr[m*128+d] = log softmax denominator of cate[m][d][*].
// One wave per (m,d) row (proven r2/r3/r5 pattern). 2048 waves.
// The gather kernel only needs K[m] = sum_d lse_arr[m*128+d]  (16 numbers),
// because sum_d logp = sum_d cate - K[m]. This removes ALL softmax work from
// the main kernel, enabling a raw-transpose LDS table with no global table.
// ---------------------------------------------------------------------------
__global__ __launch_bounds__(256) void lse_kernel(
    const float* __restrict__ cate,   // [M][D][C] f32
    float* __restrict__ lse_arr)      // [M*D] f32 (d_ws, 8 KB)
{
    const int wid  = (blockIdx.x * 256 + threadIdx.x) >> 6;  // 0..2047
    const int lane = threadIdx.x & 63;
    const int m = wid >> 7;
    const int d = wid & (DD - 1);

    const float* row = cate + (m * DD + d) * CC;
    float v = (lane < CC) ? row[lane] : -1e30f;

    float mx = v;
    #pragma unroll
    for (int off = 32; off; off >>= 1)
        mx = fmaxf(mx, __shfl_xor(mx, off, 64));
    float e = (lane < CC) ? __expf(v - mx) : 0.f;
    #pragma unroll
    for (int off = 32; off; off >>= 1)
        e += __shfl_xor(e, off, 64);

    if (lane == 0) lse_arr[wid] = mx + __logf(e);
}

// ---------------------------------------------------------------------------
// Kernel 2: fused transpose+gather, barrier-free (per-block LDS table).
// 256 blocks x 512 threads; block owns 128 batch rows.
// Per 32-d chunk:
//   T: wave w (=m-pair q) transposes rows m=2w,2w+1 into LDS: entry (dl,c)
//      = 40 B (16 bf16 in 8 u32 + 8 B pad). Loads are lane=c COALESCED
//      (200 B/row); stores ds_write_b32, ~4-way banks. No exp anywhere.
//   G: 4 lanes per row; lane l reads uint2 (m=4l..4l+3) per (d,c) event —
//      the r4-proven coalesced 4-lane-per-32B-entry pattern, now in LDS.
//      40 B stride => 8B-aligned b64 reads, bases spread over bank-pairs.
//      x shared via one byte-packed shfl per 4-d group (x read once, 16 MB).
// Epilogue: ll[m] = a[m] + logw[m] - K[m]; 4-lane logsumexp (r5 pattern).
// LDS: 64000 (table) + 64 (K) < 64 KB.
// ---------------------------------------------------------------------------
__global__ __launch_bounds__(512) void fused_gather(
    const int* __restrict__ x,        // [B][D] int32
    const float* __restrict__ mw,     // [M]
    const float* __restrict__ cate,   // [M][D][C] f32
    const float* __restrict__ lse_arr,// [M*D] from kernel 1
    float* __restrict__ out)          // [B]
{
    __shared__ __align__(16) unsigned int tb[32 * 50 * 10];  // 64000 B
    __shared__ float Klds[MM];

    const int tid  = threadIdx.x;
    const int l    = tid & 3;         // mixture-quad (m = 4l..4l+3)
    const int r    = tid >> 2;        // 0..127 row-in-block
    const int b    = blockIdx.x * 128 + r;
    const int wv   = tid >> 6;        // wave 0..7
    const int lane = tid & 63;

    // ---- K[m] reduce: 2048 lse values, deterministic shfl tree ----
    {
        const float4* la = (const float4*)lse_arr;
        float4 v4 = la[tid];                       // elems tid*4..+3, same m
        float p = (v4.x + v4.y) + (v4.z + v4.w);
        #pragma unroll
        for (int off = 16; off; off >>= 1)
            p += __shfl_xor(p, off, 64);           // stays within 32-halves
        if ((lane & 31) == 0)
            Klds[wv * 2 + (lane >> 5)] = p;        // wave w covers m=2w,2w+1
    }

    const int4* __restrict__ xr4 = (const int4*)(x + b * DD);
    float a0 = 0.f, a1 = 0.f, a2 = 0.f, a3 = 0.f;

    #pragma unroll 1
    for (int ch = 0; ch < 4; ++ch) {
        // ---- x for this chunk: lane l holds byte-packed groups 2l, 2l+1 ----
        int4 xa = xr4[ch * 8 + 2 * l];
        int4 xb = xr4[ch * 8 + 2 * l + 1];
        unsigned int pk0 = (unsigned)xa.x | ((unsigned)xa.y << 8) |
                           ((unsigned)xa.z << 16) | ((unsigned)xa.w << 24);
        unsigned int pk1 = (unsigned)xb.x | ((unsigned)xb.y << 8) |
                           ((unsigned)xb.z << 16) | ((unsigned)xb.w << 24);

        // ---- T: wave wv transposes rows m=2wv, 2wv+1 (lane = c) ----
        {
            const float* r0 = cate + ((2 * wv) * DD + ch * 32) * CC + lane;
            const float* r1 = cate + ((2 * wv + 1) * DD + ch * 32) * CC + lane;
            #pragma unroll 4
            for (int dl = 0; dl < 32; ++dl) {
                if (lane < CC) {
                    float v0 = r0[dl * CC];
                    float v1 = r1[dl * CC];
                    unsigned int b0 = __float_as_uint(v0);
                    b0 += 0x7fffu + ((b0 >> 16) & 1u);   // RNE bf16
                    unsigned int b1 = __float_as_uint(v1);
                    b1 += 0x7fffu + ((b1 >> 16) & 1u);
                    tb[(dl * 50 + lane) * 10 + wv] = (b0 >> 16) | (b1 & 0xffff0000u);
                }
            }
        }
        __syncthreads();

        // ---- G: gather this chunk's 32 d's for the block's 128 rows ----
        #pragma unroll
        for (int jj = 0; jj < 8; ++jj) {
            unsigned int c4 = __shfl((jj & 1) ? pk1 : pk0,
                                     (tid & ~3) + (jj >> 1), 64);
            #pragma unroll
            for (int k = 0; k < 4; ++k) {
                int c  = (c4 >> (8 * k)) & 0xff;
                int dl = jj * 4 + k;
                const uint2* p = (const uint2*)&tb[(dl * 50 + c) * 10 + 2 * l];
                uint2 u = *p;                       // ds_read_b64, 8B-aligned
                a0 += __uint_as_float(u.x << 16);
                a1 += __uint_as_float(u.x & 0xffff0000u);
                a2 += __uint_as_float(u.y << 16);
                a3 += __uint_as_float(u.y & 0xffff0000u);
            }
        }
        __syncthreads();
    }

    // ---- epilogue: logw (uniform recompute, r5-proven) + K correction ----
    float mmx = -1e30f;
    #pragma unroll
    for (int k = 0; k < MM; ++k) mmx = fmaxf(mmx, mw[k]);
    float sw = 0.f;
    #pragma unroll
    for (int k = 0; k < MM; ++k) sw += __expf(mw[k] - mmx);
    float lsew = mmx + __logf(sw);

    float l0 = a0 + mw[4 * l + 0] - lsew - Klds[4 * l + 0];
    float l1 = a1 + mw[4 * l + 1] - lsew - Klds[4 * l + 1];
    float l2 = a2 + mw[4 * l + 2] - lsew - Klds[4 * l + 2];
    float l3 = a3 + mw[4 * l + 3] - lsew - Klds[4 * l + 3];

    float mx = fmaxf(fmaxf(l0, l1), fmaxf(l2, l3));
    mx = fmaxf(mx, __shfl_xor(mx, 1, 64));
    mx = fmaxf(mx, __shfl_xor(mx, 2, 64));
    float e = __expf(l0 - mx) + __expf(l1 - mx) + __expf(l2 - mx) + __expf(l3 - mx);
    e += __shfl_xor(e, 1, 64);
    e += __shfl_xor(e, 2, 64);

    if (l == 0) out[b] = mx + __logf(e);
}

extern "C" void kernel_launch(void* const* d_in, const int* in_sizes, int n_in,
                              void* d_out, int out_size, void* d_ws, size_t ws_size,
                              hipStream_t stream) {
    const int*   x    = (const int*)d_in[0];     // [B][D]
    const float* mw   = (const float*)d_in[1];   // [M]
    const float* cate = (const float*)d_in[2];   // [M][D][C]
    float* out = (float*)d_out;

    float* lse_arr = (float*)d_ws;               // 2048 f32 = 8 KB

    // kernel 1: one wave per (m,d) row -> 2048 waves
    lse_kernel<<<(MM * DD) / 4, 256, 0, stream>>>(cate, lse_arr);

    // kernel 2: fused transpose+gather, 128 rows per 512-thread block
    fused_gather<<<BB / 128, 512, 0, stream>>>(x, mw, cate, lse_arr, out);
}